// Round 5
// baseline (322.410 us; speedup 1.0000x reference)
//
#include <hip/hip_runtime.h>
#include <math.h>

#define CCH 64
#define EPT 8              // edges per thread in the deposit pass
#define SPILL_CAP_MAX 262144
#define TRASH 16384        // ints per trash region (64 KB); two regions

typedef float f4v __attribute__((ext_vector_type(4)));

__device__ __forceinline__ void nt_store_f4(float4 v, float4* p) {
    f4v x; x.x = v.x; x.y = v.y; x.z = v.z; x.w = v.w;
    __builtin_nontemporal_store(x, (f4v*)p);
}

__device__ __forceinline__ float4 max4f(float4 a, float4 b) {
    return make_float4(fmaxf(a.x, b.x), fmaxf(a.y, b.y),
                       fmaxf(a.z, b.z), fmaxf(a.w, b.w));
}

__device__ __forceinline__ void atomicMaxF(float* addr, float v) {
    if (v >= 0.0f) atomicMax((int*)addr, __float_as_int(v));
    else           atomicMin((unsigned int*)addr, __float_as_uint(v));
}

// ---------------- last-resort fallback (round-1 atomic path) ----------------

__global__ __launch_bounds__(256) void fill_neginf_kernel(float4* out, int n4) {
    int i = blockIdx.x * blockDim.x + threadIdx.x;
    int stride = gridDim.x * blockDim.x;
    const float4 v = make_float4(-INFINITY, -INFINITY, -INFINITY, -INFINITY);
    for (; i < n4; i += stride) out[i] = v;
}

__global__ __launch_bounds__(256) void scatter_max_kernel(
        const float4* __restrict__ feat4, const int* __restrict__ src,
        const int* __restrict__ tgt, const int* __restrict__ ntypes,
        float* __restrict__ out, int E) {
    int gid = blockIdx.x * blockDim.x + threadIdx.x;
    int e = gid >> 4, q = gid & 15;
    if (e >= E) return;
    int n0 = ntypes[e*3+0], n1 = ntypes[e*3+1], n2 = ntypes[e*3+2];
    if ((n0 | n1 | n2) < 0) return;
    float4 f = feat4[(size_t)tgt[e] * 16 + q];
    float* o = out + (size_t)src[e] * CCH + q * 4;
    atomicMaxF(o+0, f.x); atomicMaxF(o+1, f.y);
    atomicMaxF(o+2, f.z); atomicMaxF(o+3, f.w);
}

__global__ __launch_bounds__(256) void finalize_kernel(
        float4* out, int n4, const int* feat_depth, float* scalar_slot) {
    int i = blockIdx.x * blockDim.x + threadIdx.x;
    int stride = gridDim.x * blockDim.x;
    for (; i < n4; i += stride) {
        float4 v = out[i];
        v.x = (v.x == -INFINITY) ? 0.0f : v.x;
        v.y = (v.y == -INFINITY) ? 0.0f : v.y;
        v.z = (v.z == -INFINITY) ? 0.0f : v.z;
        v.w = (v.w == -INFINITY) ? 0.0f : v.w;
        out[i] = v;
    }
    if (blockIdx.x == 0 && threadIdx.x == 0)
        scalar_slot[0] = (float)(feat_depth[0] + 1);
}

// ---------------- padded-bucket path ----------------

__global__ __launch_bounds__(256) void zero4_kernel(int4* p, long long n4) {
    long long i = blockIdx.x * (long long)blockDim.x + threadIdx.x;
    long long stride = gridDim.x * (long long)blockDim.x;
    const int4 z = make_int4(0, 0, 0, 0);
    for (; i < n4; i += stride) p[i] = z;
}

// Single edge pass. Branchless: ALL 8 atomicAdds are unconditional (masked
// edges hit a trash counter via pointer select), so they issue back-to-back
// and the 8 dependent deposit stores drain with pipelined vmcnt — one atomic
// latency exposure instead of eight.
template <int STRIDE>
__global__ __launch_bounds__(256) void fill_deposit_kernel(
        const int* __restrict__ src, const int* __restrict__ tgt,
        const int* __restrict__ ntypes, int* __restrict__ buckets,
        unsigned long long* __restrict__ spill, int spillCap,
        int* __restrict__ spillCur, int* __restrict__ trash, int E) {
    constexpr int K = STRIDE - 1;
    int tid = blockIdx.x * blockDim.x + threadIdx.x;
    long long e0 = (long long)tid * EPT;
    if (e0 >= E) return;
    if (e0 + EPT <= E) {
        union { int4 v[2]; int a[8]; } sv, tv;
        const int4* s4 = (const int4*)(src + e0);
        const int4* t4 = (const int4*)(tgt + e0);
        sv.v[0] = s4[0]; sv.v[1] = s4[1];
        tv.v[0] = t4[0]; tv.v[1] = t4[1];
        union { int4 v[6]; int a[24]; } nt;
        const int4* n4p = (const int4*)(ntypes + e0 * 3);
        #pragma unroll
        for (int i = 0; i < 6; ++i) nt.v[i] = n4p[i];

        bool ok[EPT];
        int* ap[EPT];
        #pragma unroll
        for (int i = 0; i < EPT; ++i) {
            ok[i] = (nt.a[3*i] | nt.a[3*i+1] | nt.a[3*i+2]) >= 0;
            int* b  = buckets + (size_t)sv.a[i] * STRIDE;
            int* tr = trash + (((unsigned)tid * EPT + i) & (TRASH - 1));
            ap[i] = ok[i] ? b : tr;              // cndmask, no branch
        }
        int c[EPT];
        #pragma unroll
        for (int i = 0; i < EPT; ++i) c[i] = atomicAdd(ap[i], 1);
        #pragma unroll
        for (int i = 0; i < EPT; ++i) {
            int cc = c[i];
            bool fit = ok[i] && (cc < K);
            int* st = fit ? (ap[i] + 1 + cc)
                          : (trash + TRASH + (((unsigned)tid * EPT + i) & (TRASH - 1)));
            *st = tv.a[i];                        // unconditional store
            if (ok[i] && cc >= K) {               // rare spill
                int sp = atomicAdd(spillCur, 1);
                if (sp < spillCap) {
                    unsigned long long pk =
                        ((unsigned long long)(unsigned)sv.a[i] << 32) | (unsigned)tv.a[i];
                    spill[sp] = pk;
                }
            }
        }
    } else {
        for (long long e = e0; e < E; ++e) {
            if ((ntypes[e*3] | ntypes[e*3+1] | ntypes[e*3+2]) >= 0) {
                int r = src[e], t = tgt[e];
                int* b = buckets + (size_t)r * STRIDE;
                int c = atomicAdd(b, 1);
                if (c < K) {
                    b[1 + c] = t;
                } else {
                    int sp = atomicAdd(spillCur, 1);
                    if (sp < spillCap) {
                        unsigned long long pk =
                            ((unsigned long long)(unsigned)r << 32) | (unsigned)t;
                        spill[sp] = pk;
                    }
                }
            }
        }
    }
}

// One 16-lane group per row: whole bucket line -> registers, then clamped
// fully-unrolled gathers in quads (4-wide memory ILP, static reg indexing).
template <int STRIDE>
__global__ __launch_bounds__(256) void gather_bucket_kernel(
        const float4* __restrict__ feat4, const int* __restrict__ buckets,
        float4* __restrict__ out4, int N,
        const int* __restrict__ feat_depth, float* __restrict__ scalar_slot) {
    constexpr int K = STRIDE - 1;
    int gid = blockIdx.x * blockDim.x + threadIdx.x;
    if (gid == 0) scalar_slot[0] = (float)(feat_depth[0] + 1);
    int r = gid >> 4, q = gid & 15;
    if (r >= N) return;
    const int* b = buckets + (size_t)r * STRIDE;
    int va[STRIDE];
    #pragma unroll
    for (int w = 0; w < STRIDE / 4; ++w) {
        int4 x = ((const int4*)b)[w];
        va[4*w+0] = x.x; va[4*w+1] = x.y; va[4*w+2] = x.z; va[4*w+3] = x.w;
    }
    int cnt = va[0];
    int m = cnt < K ? cnt : K;            // valid slots are 1..m
    float4 acc;
    if (m <= 0) {
        acc = make_float4(0.0f, 0.0f, 0.0f, 0.0f);
    } else {
        int t0 = va[1];
        acc = feat4[(size_t)t0 * 16 + q];
        #pragma unroll
        for (int base = 2; base <= K; base += 4) {
            if (base <= m) {
                #pragma unroll
                for (int s = base; s < base + 4; ++s) {
                    if (s <= K) {
                        int t = (s <= m) ? va[s] : t0;   // clamped dup -> L1 hit
                        acc = max4f(acc, feat4[(size_t)t * 16 + q]);
                    }
                }
            }
        }
    }
    nt_store_f4(acc, out4 + (size_t)r * 16 + q);
}

// Resolve spilled edges (rare): atomic max on top of gather output (only raises).
__global__ __launch_bounds__(256) void spill_kernel(
        const float4* __restrict__ feat4,
        const unsigned long long* __restrict__ spill,
        const int* __restrict__ spillCur, int spillCap,
        float* __restrict__ out) {
    int n = *spillCur; if (n > spillCap) n = spillCap;
    long long total = (long long)n * 16;
    long long stride = (long long)gridDim.x * blockDim.x;
    for (long long i = blockIdx.x * (long long)blockDim.x + threadIdx.x;
         i < total; i += stride) {
        int e = (int)(i >> 4), q = (int)(i & 15);
        unsigned long long pk = spill[e];
        int r = (int)(pk >> 32);
        int t = (int)(pk & 0xffffffffu);
        float4 f = feat4[(size_t)t * 16 + q];
        float* o = out + (size_t)r * CCH + q * 4;
        atomicMaxF(o+0, f.x); atomicMaxF(o+1, f.y);
        atomicMaxF(o+2, f.z); atomicMaxF(o+3, f.w);
    }
}

// If the spill list overflowed (never expected), rescan ALL edges with atomic
// max — idempotent and only raises values, so it is correct on top of gather.
__global__ __launch_bounds__(256) void repair_kernel(
        const float4* __restrict__ feat4, const int* __restrict__ src,
        const int* __restrict__ tgt, const int* __restrict__ ntypes,
        const int* __restrict__ spillCur, int spillCap,
        float* __restrict__ out, int E) {
    if (*spillCur <= spillCap) return;
    long long total = (long long)E * 16;
    long long stride = (long long)gridDim.x * blockDim.x;
    for (long long i = blockIdx.x * (long long)blockDim.x + threadIdx.x;
         i < total; i += stride) {
        int e = (int)(i >> 4), q = (int)(i & 15);
        if ((ntypes[e*3] | ntypes[e*3+1] | ntypes[e*3+2]) < 0) continue;
        float4 f = feat4[(size_t)tgt[e] * 16 + q];
        float* o = out + (size_t)src[e] * CCH + q * 4;
        atomicMaxF(o+0, f.x); atomicMaxF(o+1, f.y);
        atomicMaxF(o+2, f.z); atomicMaxF(o+3, f.w);
    }
}

extern "C" void kernel_launch(void* const* d_in, const int* in_sizes, int n_in,
                              void* d_out, int out_size, void* d_ws, size_t ws_size,
                              hipStream_t stream) {
    const float* feat       = (const float*)d_in[0];
    const int*   src_ids    = (const int*)d_in[1];
    const int*   tgt_ids    = (const int*)d_in[2];
    const int*   ntypes     = (const int*)d_in[3];
    const int*   feat_depth = (const int*)d_in[5];
    float* out = (float*)d_out;

    const int E = in_sizes[1];
    const int nout_elems = out_size - 1;
    const int N = nout_elems / CCH;      // output rows
    const int n4 = nout_elems / 4;

    // pick the largest bucket stride that fits the workspace
    size_t wsInts = ws_size / sizeof(int);
    int stride = 0;
    for (int s = 16; s >= 8; s -= 4) {
        size_t need = (size_t)N * s + 16 + 2ull * 4096 + 2ull * TRASH;
        if (need <= wsInts) { stride = s; break; }
    }

    if (stride == 0) {
        // last-resort: atomic scatter-max
        fill_neginf_kernel<<<2048, 256, 0, stream>>>((float4*)out, n4);
        long long total = (long long)E * 16;
        int blocks = (int)((total + 255) / 256);
        scatter_max_kernel<<<blocks, 256, 0, stream>>>(
            (const float4*)feat, src_ids, tgt_ids, ntypes, out, E);
        finalize_kernel<<<2048, 256, 0, stream>>>(
            (float4*)out, n4, feat_depth, out + nout_elems);
        return;
    }

    int* buckets  = (int*)d_ws;
    int* spillCur = buckets + (size_t)N * stride;          // 16-int block, [0]=cursor
    unsigned long long* spill = (unsigned long long*)(spillCur + 16);
    size_t rem = wsInts - (size_t)N * stride - 16 - 2ull * TRASH;
    long long scap = (long long)(rem / 2);
    if (scap > SPILL_CAP_MAX) scap = SPILL_CAP_MAX;
    int spillCap = (int)scap;
    int* trash = (int*)(spill + spillCap);                  // 2*TRASH ints, garbage ok

    long long zn4 = ((long long)N * stride + 16) / 4;
    zero4_kernel<<<2048, 256, 0, stream>>>((int4*)d_ws, zn4);

    long long eThreads = ((long long)E + EPT - 1) / EPT;
    int eBlocks = (int)((eThreads + 255) / 256);
    long long gthreads = (long long)N * 16;
    int gBlocks = (int)((gthreads + 255) / 256);

    if (stride == 16) {
        fill_deposit_kernel<16><<<eBlocks, 256, 0, stream>>>(
            src_ids, tgt_ids, ntypes, buckets, spill, spillCap, spillCur, trash, E);
        gather_bucket_kernel<16><<<gBlocks, 256, 0, stream>>>(
            (const float4*)feat, buckets, (float4*)out, N,
            feat_depth, out + nout_elems);
    } else if (stride == 12) {
        fill_deposit_kernel<12><<<eBlocks, 256, 0, stream>>>(
            src_ids, tgt_ids, ntypes, buckets, spill, spillCap, spillCur, trash, E);
        gather_bucket_kernel<12><<<gBlocks, 256, 0, stream>>>(
            (const float4*)feat, buckets, (float4*)out, N,
            feat_depth, out + nout_elems);
    } else {
        fill_deposit_kernel<8><<<eBlocks, 256, 0, stream>>>(
            src_ids, tgt_ids, ntypes, buckets, spill, spillCap, spillCur, trash, E);
        gather_bucket_kernel<8><<<gBlocks, 256, 0, stream>>>(
            (const float4*)feat, buckets, (float4*)out, N,
            feat_depth, out + nout_elems);
    }

    spill_kernel<<<2048, 256, 0, stream>>>(
        (const float4*)feat, spill, spillCur, spillCap, out);
    repair_kernel<<<4096, 256, 0, stream>>>(
        (const float4*)feat, src_ids, tgt_ids, ntypes,
        spillCur, spillCap, out, E);
}